// Round 9
// baseline (292.301 us; speedup 1.0000x reference)
//
#include <hip/hip_runtime.h>
#include <math.h>

#define BATCH  2
#define SEQ    1024
#define HIDDEN 1024
#define NHEADS 8
#define DHEAD  128
#define NTOK   (BATCH*SEQ)
#define GEPS   1e-5f

typedef float f32x16 __attribute__((ext_vector_type(16)));
typedef __bf16 bf16x8 __attribute__((ext_vector_type(8)));
typedef unsigned int u32x4 __attribute__((ext_vector_type(4)));

union Frag { u32x4 u; bf16x8 h; };

__device__ __forceinline__ unsigned short f2bf(float f) {
    unsigned int u = __float_as_uint(f);
    unsigned int r = (u + 0x7FFFu + ((u >> 16) & 1u)) >> 16;
    return (unsigned short)r;
}

// complex swish: z * sigmoid(z)
__device__ __forceinline__ void cswish(float zr, float zi, float& outr, float& outi) {
    const float e = expf(-zr);
    float sg, cg;
    sincosf(zi, &sg, &cg);
    const float wr = fmaf(e, cg, 1.0f);   // 1 + e^{-zr} cos(zi)
    const float wi = -e*sg;               // -e^{-zr} sin(zi)
    const float inv = 1.0f / fmaf(wr, wr, wi*wi);
    outr = (zr*wr + zi*wi)*inv;
    outi = (zi*wr - zr*wi)*inv;
}

// ---------------------------------------------------------------------------
// gamma decay table
// ---------------------------------------------------------------------------
__global__ void gpow_kernel(float* __restrict__ gpow) {
    const int h = blockIdx.x;
    const int k = threadIdx.x;
    const float l = fmaf((float)h, -0.39608410317711170f, -3.46573590279972650f);
    const float gamma = 1.0f - expf(l);
    gpow[h*SEQ + k] = powf(gamma, (float)k);
}

// ---------------------------------------------------------------------------
// per-head projections + RoPE phases -> bf16 Q,K; fp32 V.
// ---------------------------------------------------------------------------
__global__ __launch_bounds__(256) void proj_kernel(
    const float* __restrict__ X,
    const float* __restrict__ Wq, const float* __restrict__ Wk, const float* __restrict__ Wv,
    const float* __restrict__ theta,
    unsigned short* __restrict__ Qbre, unsigned short* __restrict__ Qbim,
    unsigned short* __restrict__ Kbre, unsigned short* __restrict__ Kbim,
    float* __restrict__ vv)
{
    const int tt  = blockIdx.x;
    const int h   = blockIdx.y;
    const int mt  = blockIdx.z;   // 0:q 1:k 2:v
    const int tid = threadIdx.x;

    __shared__ __align__(16) float Xs[64][132];

    for (int i = tid*4; i < 64*128; i += 1024) {
        const int r = i >> 7, c = i & 127;
        *(float4*)&Xs[r][c] = *(const float4*)&X[(size_t)(tt*64 + r)*HIDDEN + h*DHEAD + c];
    }
    __syncthreads();

    const float* W = ((mt == 0) ? Wq : (mt == 1) ? Wk : Wv) + (size_t)h*DHEAD*DHEAD;
    const int tx = tid & 31, ty = tid >> 5;

    float a0[8], a1[8], a2[8], a3[8];
    #pragma unroll
    for (int j = 0; j < 8; ++j) { a0[j]=0.f; a1[j]=0.f; a2[j]=0.f; a3[j]=0.f; }

    #pragma unroll 4
    for (int k = 0; k < DHEAD; ++k) {
        const float4 w = *(const float4*)&W[k*DHEAD + tx*4];
        #pragma unroll
        for (int j = 0; j < 8; ++j) {
            const float x = Xs[ty*8 + j][k];
            a0[j] = fmaf(x, w.x, a0[j]);
            a1[j] = fmaf(x, w.y, a1[j]);
            a2[j] = fmaf(x, w.z, a2[j]);
            a3[j] = fmaf(x, w.w, a3[j]);
        }
    }

    const int d0 = tx*4;
    const float th0 = theta[h*DHEAD + d0 + 0];
    const float th1 = theta[h*DHEAD + d0 + 1];
    const float th2 = theta[h*DHEAD + d0 + 2];
    const float th3 = theta[h*DHEAD + d0 + 3];

    #pragma unroll
    for (int j = 0; j < 8; ++j) {
        const int t = tt*64 + ty*8 + j;
        const size_t g = (size_t)t*HIDDEN + h*DHEAD + d0;
        if (mt == 2) {
            float4 o; o.x=a0[j]; o.y=a1[j]; o.z=a2[j]; o.w=a3[j];
            *(float4*)&vv[g] = o;
        } else {
            const float np1 = (float)((t & (SEQ-1)) + 1);
            float s0,c0,s1,c1,s2,c2,s3,c3;
            sincosf(np1*th0, &s0, &c0);
            sincosf(np1*th1, &s1, &c1);
            sincosf(np1*th2, &s2, &c2);
            sincosf(np1*th3, &s3, &c3);
            float rex = a0[j]*c0, rey = a1[j]*c1, rez = a2[j]*c2, rew = a3[j]*c3;
            float imx, imy, imz, imw;
            if (mt == 0) { imx = a0[j]*s0; imy = a1[j]*s1; imz = a2[j]*s2; imw = a3[j]*s3; }
            else         { imx = -a0[j]*s0; imy = -a1[j]*s1; imz = -a2[j]*s2; imw = -a3[j]*s3; }
            ushort4 o1 = make_ushort4(f2bf(rex), f2bf(rey), f2bf(rez), f2bf(rew));
            ushort4 o2 = make_ushort4(f2bf(imx), f2bf(imy), f2bf(imz), f2bf(imw));
            if (mt == 0) { *(ushort4*)&Qbre[g] = o1; *(ushort4*)&Qbim[g] = o2; }
            else         { *(ushort4*)&Kbre[g] = o1; *(ushort4*)&Kbim[g] = o2; }
        }
    }
}

// ---------------------------------------------------------------------------
// V transpose: vv fp32 [token][h*128+d] -> Vtb bf16 [bh][d][s]
// ---------------------------------------------------------------------------
__global__ __launch_bounds__(256) void vt_kernel(
    const float* __restrict__ vv, unsigned short* __restrict__ Vtb)
{
    const int st  = blockIdx.x;
    const int h   = blockIdx.y;
    const int tid = threadIdx.x;
    const int b  = st >> 4;
    const int s0 = (st & 15)*64;

    __shared__ __align__(16) float Vs[64][132];

    for (int i = tid*4; i < 64*128; i += 1024) {
        const int r = i >> 7, c = i & 127;
        *(float4*)&Vs[r][c] = *(const float4*)&vv[(size_t)(st*64 + r)*HIDDEN + h*DHEAD + c];
    }
    __syncthreads();

    const int d = tid & 127, seg = tid >> 7;
    unsigned short* dst = Vtb + ((size_t)((b*NHEADS + h)*DHEAD + d))*SEQ + s0 + seg*32;
    #pragma unroll
    for (int j = 0; j < 32; j += 2) {
        unsigned int u = (unsigned)f2bf(Vs[seg*32+j][d]) | ((unsigned)f2bf(Vs[seg*32+j+1][d]) << 16);
        *(unsigned int*)(dst + j) = u;
    }
}

// ---------------------------------------------------------------------------
// retention attention, MFMA bf16.
// Round-5 structure (2 waves/block split the causal m-range, all state in
// registers, XCD-chunked grid) + A/B register double-buffer prefetch of K,V:
// loads for iteration m+1 are issued before computing iteration m, hiding
// L2 latency inside the wave. 1 wave/SIMD, ~450 unified regs, no spills.
// ---------------------------------------------------------------------------
#define CVTPK(dst, a, b) asm("v_cvt_pk_bf16_f32 %0, %1, %2" : "=v"(dst) : "v"(a), "v"(b))
#define SWAP32(x, y)     asm("v_permlane32_swap_b32 %0, %1" : "+v"(x), "+v"(y))

#define LOADKV(KR, KI, VF, mm) do {                                            \
    const int kv0_ = (mm)*32;                                                  \
    const unsigned short* kr_ = Kbre + bhoff + (size_t)(kv0_ + l31)*HIDDEN + 8*hi; \
    const unsigned short* ki_ = Kbim + bhoff + (size_t)(kv0_ + l31)*HIDDEN + 8*hi; \
    _Pragma("unroll")                                                          \
    for (int ks = 0; ks < 8; ++ks) {                                           \
        KR[ks].u = *(const u32x4*)(kr_ + 16*ks);                               \
        KI[ks].u = *(const u32x4*)(ki_ + 16*ks);                               \
    }                                                                          \
    _Pragma("unroll")                                                          \
    for (int dt = 0; dt < 4; ++dt)                                             \
        _Pragma("unroll")                                                      \
        for (int ks2 = 0; ks2 < 2; ++ks2)                                      \
            VF[dt][ks2].u = *(const u32x4*)(Vtb                                \
                + ((size_t)(bh*DHEAD + dt*32 + l31))*SEQ + kv0_ + 16*ks2 + 8*hi); \
} while (0)

#define STEP(KR, KI, VF, mm) do {                                              \
    const int base_ = 32*(qt - (mm)) + l31;                                    \
    const float g1_ = gp[base_];                                               \
    f32x16 SR_, SI_;                                                           \
    _Pragma("unroll")                                                          \
    for (int e = 0; e < 16; ++e) { SR_[e] = 0.f; SI_[e] = 0.f; }               \
    _Pragma("unroll")                                                          \
    for (int ks = 0; ks < 8; ++ks) {                                           \
        Frag qn_;                                                              \
        _Pragma("unroll")                                                      \
        for (int e = 0; e < 4; ++e) qn_.u[e] = Qi[ks].u[e] ^ 0x80008000u;      \
        SR_ = __builtin_amdgcn_mfma_f32_32x32x16_bf16(KR[ks].h, Qr[ks].h, SR_, 0, 0, 0); \
        SI_ = __builtin_amdgcn_mfma_f32_32x32x16_bf16(KR[ks].h, Qi[ks].h, SI_, 0, 0, 0); \
        SR_ = __builtin_amdgcn_mfma_f32_32x32x16_bf16(KI[ks].h, qn_.h, SR_, 0, 0, 0);    \
        SI_ = __builtin_amdgcn_mfma_f32_32x32x16_bf16(KI[ks].h, Qr[ks].h, SI_, 0, 0, 0); \
    }                                                                          \
    float pr_[16], pi_[16];                                                    \
    _Pragma("unroll")                                                          \
    for (int r = 0; r < 16; ++r) {                                             \
        const float w_ = (base_ >= crw[r]) ? g1_*ginv[r] : 0.0f;               \
        pr_[r] = SR_[r]*w_;                                                    \
        pi_[r] = SI_[r]*w_;                                                    \
    }                                                                          \
    Frag PR_[2], PI_[2];                                                       \
    _Pragma("unroll")                                                          \
    for (int ks2 = 0; ks2 < 2; ++ks2) {                                        \
        const int o_ = ks2*8;                                                  \
        unsigned int a0_, b0_, a1_, b1_;                                       \
        CVTPK(a0_, pr_[o_+0], pr_[o_+1]);                                      \
        CVTPK(b0_, pr_[o_+4], pr_[o_+5]);                                      \
        SWAP32(a0_, b0_);                                                      \
        CVTPK(a1_, pr_[o_+2], pr_[o_+3]);                                      \
        CVTPK(b1_, pr_[o_+6], pr_[o_+7]);                                      \
        SWAP32(a1_, b1_);                                                      \
        PR_[ks2].u[0] = a0_; PR_[ks2].u[1] = a1_; PR_[ks2].u[2] = b0_; PR_[ks2].u[3] = b1_; \
        CVTPK(a0_, pi_[o_+0], pi_[o_+1]);                                      \
        CVTPK(b0_, pi_[o_+4], pi_[o_+5]);                                      \
        SWAP32(a0_, b0_);                                                      \
        CVTPK(a1_, pi_[o_+2], pi_[o_+3]);                                      \
        CVTPK(b1_, pi_[o_+6], pi_[o_+7]);                                      \
        SWAP32(a1_, b1_);                                                      \
        PI_[ks2].u[0] = a0_; PI_[ks2].u[1] = a1_; PI_[ks2].u[2] = b0_; PI_[ks2].u[3] = b1_; \
    }                                                                          \
    _Pragma("unroll")                                                          \
    for (int dt = 0; dt < 4; ++dt) {                                           \
        Yr[dt] = __builtin_amdgcn_mfma_f32_32x32x16_bf16(VF[dt][0].h, PR_[0].h, Yr[dt], 0, 0, 0); \
        Yr[dt] = __builtin_amdgcn_mfma_f32_32x32x16_bf16(VF[dt][1].h, PR_[1].h, Yr[dt], 0, 0, 0); \
        Yi[dt] = __builtin_amdgcn_mfma_f32_32x32x16_bf16(VF[dt][0].h, PI_[0].h, Yi[dt], 0, 0, 0); \
        Yi[dt] = __builtin_amdgcn_mfma_f32_32x32x16_bf16(VF[dt][1].h, PI_[1].h, Yi[dt], 0, 0, 0); \
    }                                                                          \
} while (0)

__global__ __launch_bounds__(128)
__attribute__((amdgpu_waves_per_eu(1, 1)))
void attn_kernel(
    const unsigned short* __restrict__ Qbre, const unsigned short* __restrict__ Qbim,
    const unsigned short* __restrict__ Kbre, const unsigned short* __restrict__ Kbim,
    const unsigned short* __restrict__ Vtb,  const float* __restrict__ gpow,
    float* __restrict__ yre, float* __restrict__ yim)
{
    const int tid  = threadIdx.x;
    const int lane = tid & 63;
    const int wv   = tid >> 6;
    const int l31 = lane & 31, hi = (lane >> 5) & 1;

    // XCD-chunked decode: id%8 = bh>>1  (each XCD owns 2 (b,h) pairs)
    const int id = blockIdx.x;
    const int bh = ((id & 7) << 1) | ((id >> 3) & 1);
    const int qt = id >> 4;

    const int b = bh >> 3, h = bh & 7;
    const int q0 = qt * 32;
    const size_t bhoff = (size_t)b*SEQ*HIDDEN + h*DHEAD;
    const float* gp = gpow + h*SEQ;

    __shared__ float Yt2[32][133];

    int   crw[16];
    float ginv[16];
    #pragma unroll
    for (int r = 0; r < 16; ++r) {
        const int cr = (r & 3) + 8*(r >> 2) + 4*hi;
        crw[r] = cr;
        ginv[r] = 1.0f / gp[cr];
    }

    Frag Qr[8], Qi[8];
    {
        const unsigned short* qr = Qbre + bhoff + (size_t)(q0 + l31)*HIDDEN + 8*hi;
        const unsigned short* qi = Qbim + bhoff + (size_t)(q0 + l31)*HIDDEN + 8*hi;
        #pragma unroll
        for (int ks = 0; ks < 8; ++ks) {
            Qr[ks].u = *(const u32x4*)(qr + 16*ks);
            Qi[ks].u = *(const u32x4*)(qi + 16*ks);
        }
    }

    f32x16 Yr[4], Yi[4];
    #pragma unroll
    for (int dt = 0; dt < 4; ++dt)
        #pragma unroll
        for (int e = 0; e < 16; ++e) { Yr[dt][e] = 0.f; Yi[dt][e] = 0.f; }

    // m-range split across the 2 waves
    const int nm   = qt + 1;
    const int half = (nm + 1) >> 1;
    const int mlo  = wv ? half : 0;
    const int mhi_ = wv ? nm   : half;

    // A/B register double-buffer prefetch over m
    Frag KrA[8], KiA[8], VfA[4][2];
    Frag KrB[8], KiB[8], VfB[4][2];

    int m = mlo;
    if (m < mhi_) {
        LOADKV(KrA, KiA, VfA, m);
        while (true) {
            if (m + 1 < mhi_) LOADKV(KrB, KiB, VfB, m + 1);
            STEP(KrA, KiA, VfA, m);
            ++m;
            if (m >= mhi_) break;
            if (m + 1 < mhi_) LOADKV(KrA, KiA, VfA, m + 1);
            STEP(KrB, KiB, VfB, m);
            ++m;
            if (m >= mhi_) break;
        }
    }

    // combine the 2 waves' partials + transposed coalesced store
    #pragma unroll
    for (int part = 0; part < 2; ++part) {
        if (part) __syncthreads();
        if (wv == 0) {
            #pragma unroll
            for (int dt = 0; dt < 4; ++dt)
                #pragma unroll
                for (int r = 0; r < 16; ++r)
                    Yt2[l31][dt*32 + crw[r]] = part ? Yi[dt][r] : Yr[dt][r];
        }
        __syncthreads();
        if (wv == 1) {
            #pragma unroll
            for (int dt = 0; dt < 4; ++dt)
                #pragma unroll
                for (int r = 0; r < 16; ++r)
                    Yt2[l31][dt*32 + crw[r]] += part ? Yi[dt][r] : Yr[dt][r];
        }
        __syncthreads();
        const int t = tid >> 2, q4 = tid & 3;
        float* dst = (part ? yim : yre) + bhoff + (size_t)(q0 + t)*HIDDEN + q4*32;
        #pragma unroll
        for (int j = 0; j < 8; ++j) {
            float4 o;
            o.x = Yt2[t][q4*32 + 4*j + 0];
            o.y = Yt2[t][q4*32 + 4*j + 1];
            o.z = Yt2[t][q4*32 + 4*j + 2];
            o.w = Yt2[t][q4*32 + 4*j + 3];
            *(float4*)(dst + 4*j) = o;
        }
    }
}

// ---------------------------------------------------------------------------
// X fp32 -> bf16 pack
// ---------------------------------------------------------------------------
__global__ __launch_bounds__(256) void xprep_kernel(
    const float* __restrict__ X, unsigned short* __restrict__ Xb)
{
    const size_t i = ((size_t)blockIdx.x*256 + threadIdx.x)*8;
    const float4 a = *(const float4*)&X[i];
    const float4 b = *(const float4*)&X[i+4];
    __align__(16) unsigned short t[8] = { f2bf(a.x), f2bf(a.y), f2bf(a.z), f2bf(a.w),
                                          f2bf(b.x), f2bf(b.y), f2bf(b.z), f2bf(b.w) };
    *(u32x4*)&Xb[i] = *(u32x4*)t;
}

// ---------------------------------------------------------------------------
// Bgt[n][k] = (n<1024 ? Wgre : Wgim)[k][n&1023]  -- bf16, [2048][1024]
// ---------------------------------------------------------------------------
__global__ __launch_bounds__(256) void wprep_g_kernel(
    const float* __restrict__ Wgre, const float* __restrict__ Wgim,
    unsigned short* __restrict__ Bgt)
{
    const int n0 = blockIdx.x*64, k0 = blockIdx.y*64;
    const float* src = (n0 < HIDDEN) ? Wgre : Wgim;
    const int nc = n0 & (HIDDEN-1);
    __shared__ float Ws[64][65];
    const int tid = threadIdx.x;
    #pragma unroll
    for (int it = 0; it < 4; ++it) {
        const int r = (tid >> 4) + it*16, c = (tid & 15)*4;
        *(float4*)&Ws[r][c] = *(const float4*)&src[(size_t)(k0 + r)*HIDDEN + nc + c];
    }
    __syncthreads();
    const int nl = tid >> 2, seg = (tid & 3)*16;
    __align__(16) unsigned short t[16];
    #pragma unroll
    for (int j = 0; j < 16; ++j) t[j] = f2bf(Ws[seg + j][nl]);
    u32x4* d = (u32x4*)&Bgt[(size_t)(n0 + nl)*HIDDEN + k0 + seg];
    d[0] = ((u32x4*)t)[0];
    d[1] = ((u32x4*)t)[1];
}

// ---------------------------------------------------------------------------
// Bot[n][k] (bf16, [1024][2048]):
//   imMode=0: k<1024 ?  Wore[k][n] : -Woim[k-1024][n]   (real-part weights)
//   imMode=1: k<1024 ?  Woim[k][n] :  Wore[k-1024][n]   (imag-part weights)
// ---------------------------------------------------------------------------
__global__ __launch_bounds__(256) void wprep_o_kernel(
    const float* __restrict__ Wore, const float* __restrict__ Woim,
    unsigned short* __restrict__ Bot, const int imMode)
{
    const int n0 = blockIdx.x*64, k0 = blockIdx.y*64;
    const float* src;
    float sign = 1.0f;
    if (!imMode) { if (k0 < HIDDEN) src = Wore; else { src = Woim; sign = -1.0f; } }
    else         { src = (k0 < HIDDEN) ? Woim : Wore; }
    const int kc = k0 & (HIDDEN-1);
    __shared__ float Ws[64][65];
    const int tid = threadIdx.x;
    #pragma unroll
    for (int it = 0; it < 4; ++it) {
        const int r = (tid >> 4) + it*16, c = (tid & 15)*4;
        const float4 v = *(const float4*)&src[(size_t)(kc + r)*HIDDEN + n0 + c];
        Ws[r][c+0] = v.x*sign; Ws[r][c+1] = v.y*sign; Ws[r][c+2] = v.z*sign; Ws[r][c+3] = v.w*sign;
    }
    __syncthreads();
    const int nl = tid >> 2, seg = (tid & 3)*16;
    __align__(16) unsigned short t[16];
    #pragma unroll
    for (int j = 0; j < 16; ++j) t[j] = f2bf(Ws[seg + j][nl]);
    u32x4* d = (u32x4*)&Bot[(size_t)(n0 + nl)*(2*HIDDEN) + k0 + seg];
    d[0] = ((u32x4*)t)[0];
    d[1] = ((u32x4*)t)[1];
}

// ---------------------------------------------------------------------------
// generic bf16 MFMA GEMM: C[M][N] = A[M][K] @ Bt[N][K]^T
// 128x128 tile, BK=64, 4 waves (2x2 of 32x32x16 frags each).
// mode 0: plain fp32 store; mode 1/2: interleaved complex re/im store.
// ---------------------------------------------------------------------------
__global__ __launch_bounds__(256) void gemm_bf16_kernel(
    const unsigned short* __restrict__ A,
    const unsigned short* __restrict__ Bt,
    float* __restrict__ C,
    const int K, const int N, const int mode)
{
    __shared__ __align__(16) unsigned short As[128][72];
    __shared__ __align__(16) unsigned short Bs[128][72];

    const int tid = threadIdx.x;
    const int mb = blockIdx.x, nb = blockIdx.y;
    const int lane = tid & 63, w = tid >> 6;
    const int l31 = lane & 31, hi = lane >> 5;
    const int wm = (w >> 1) * 64, wn = (w & 1) * 64;

    const int srow = tid >> 2;          // 0..63
    const int sseg = (tid & 3) * 16;    // 0,16,32,48 (full 64-col tile)

    const unsigned short* ga = A  + (size_t)(mb*128 + srow)*K + sseg;
    const unsigned short* gb = Bt + (size_t)(nb*128 + srow)*K + sseg;

    f32x16 acc00, acc01, acc10, acc11;
    #pragma unroll
    for (int e = 0; e < 16; ++e) { acc00[e]=0.f; acc01[e]=0.f; acc10[e]=0.f; acc11[e]=0.f; }

    u32x4 ra0 = *(const u32x4*)(ga);
    u32x4 ra1 = *(const u32x4*)(ga + 8);
    u32x4 ra2 = *(const u32x4*)(ga + (size_t)64*K);
    u32x4 ra3 = *(const u32x4*)(ga + (size_t)64*K + 8);
    u32x4 rb0 = *(const u32x4*)(gb);
    u32x4 rb1 = *(const u32x4*)(gb + 8);
    u32x4 rb2 = *(const u32x4*)(gb + (size_t)64*K);
    u32x4 rb3 = *(const u32x4*)(gb + (size_t)64*K + 8);

    for (int kk = 0; kk < K; kk += 64) {
        __syncthreads();
        *(u32x4*)&As[srow][sseg]          = ra0;
        *(u32x4*)&As[srow][sseg + 8]      = ra1;
        *(u32x4*)&As[srow + 64][sseg]     = ra2;
        *(u32x4*)&As[srow + 64][sseg + 8] = ra3;
        *(u32x4*)&Bs[srow][sseg]          = rb0;
        *(u32x4*)&Bs[srow][sseg + 8]      = rb1;
        *(u32x4*)&Bs[srow + 64][sseg]     = rb2;
        *(u32x4*)&Bs[srow + 64][sseg + 8] = rb3;
        if (kk + 64 < K) {
            const int o = kk + 64;
            ra0 = *(const u32x4*)(ga + o);
            ra1 = *(const u32x4*)(ga + o + 8);
            ra2 = *(const u32x4*)(ga + (size_t)64*K + o);
            ra3 = *(const u32x4*)(ga + (size_t)64*K + o + 8);
            rb0 = *(const u32x4*)(gb + o);
            rb1 = *(const u32x4*)(gb + o + 8);
            rb2 = *(const u32x4*)(gb + (size_t)64*K + o);
            rb3 = *(const u32x4*)(gb + (size_t)64*K + o + 8);
        }
        __syncthreads();
        #pragma unroll
        for (int ks = 0; ks < 4; ++ks) {
            Frag a0, a1, b0, b1;
            a0.u = *(const u32x4*)&As[wm + l31     ][ks*16 + hi*8];
            a1.u = *(const u32x4*)&As[wm + l31 + 32][ks*16 + hi*8];
            b0.u = *(const u32x4*)&Bs[wn + l31     ][ks*16 + hi*8];
            b1.u = *(const u32x4*)&Bs[wn + l31 + 32][ks*16 + hi*8];
            acc00 = __builtin_amdgcn_mfma_f32_32x32x16_bf16(a0.h, b0.h, acc00, 0, 0, 0);
            acc01 = __builtin_amdgcn_mfma_f32_32x32x16_bf16(a0.h, b1.h, acc01, 0, 0, 0);
            acc10 = __builtin_amdgcn_mfma_f32_32x32x16_bf16(a1.h, b0.h, acc10, 0, 0, 0);
            acc11 = __builtin_amdgcn_mfma_f32_32x32x16_bf16(a1.h, b1.h, acc11, 0, 0, 0);
        }
    }

    const int cb = nb*128 + wn + l31;
    #pragma unroll
    for (int i = 0; i < 2; ++i) {
        const f32x16& c0 = i ? acc10 : acc00;
        const f32x16& c1 = i ? acc11 : acc01;
        #pragma unroll
        for (int r = 0; r < 16; ++r) {
            const int row = mb*128 + wm + 32*i + (r & 3) + 8*(r >> 2) + 4*hi;
            if (mode == 0) {
                float* cr = C + (size_t)row*N + cb;
                cr[0]  = c0[r];
                cr[32] = c1[r];
            } else {
                float* cr = C + ((size_t)row*N + cb)*2 + (mode - 1);
                cr[0]  = c0[r];
                cr[64] = c1[r];
            }
        }
    }
}

// ---------------------------------------------------------------------------
// fused: group-norm(Y) + swish(G) + add -> Aout bf16 [2048][2048] (Zr | Zi)
// ---------------------------------------------------------------------------
__global__ __launch_bounds__(256) void znorm_kernel(
    const float* __restrict__ yre, const float* __restrict__ yim,
    const float* __restrict__ Graw,
    const float* __restrict__ w, const float* __restrict__ bbv,
    unsigned short* __restrict__ Aout)
{
    const int row  = blockIdx.x;
    const int wv   = threadIdx.x >> 6;
    const int lane = threadIdx.x & 63;

    #pragma unroll
    for (int gi = 0; gi < 2; ++gi) {
        const int h = wv*2 + gi;
        const size_t base = (size_t)row*HIDDEN + h*DHEAD;

        const float r0 = yre[base + lane];
        const float r1 = yre[base + lane + 64];
        const float i0 = yim[base + lane];
        const float i1 = yim[base + lane + 64];

        float sr = r0 + r1, si = i0 + i1;
        #pragma unroll
        for (int off = 32; off > 0; off >>= 1) {
            sr += __shfl_xor(sr, off);
            si += __shfl_xor(si, off);
        }
        const float mr = sr * (1.0f/128.0f), mi = si * (1.0f/128.0f);
        const float d0r = r0 - mr, d1r = r1 - mr, d0i = i0 - mi, d1i = i1 - mi;
        float vs = d0r*d0r + d0i*d0i + d1r*d1r + d1i*d1i;
        #pragma unroll
        for (int off = 32; off > 0; off >>= 1) vs += __shfl_xor(vs, off);
        const float scale = 1.0f / sqrtf(vs * (1.0f/127.0f) + GEPS);

        const float w0 = w[h*DHEAD + lane],   w1 = w[h*DHEAD + lane + 64];
        const float b0 = bbv[h*DHEAD + lane], b1 = bbv[h*DHEAD + lane + 64];
        const float zr0 = fmaf(d0r*scale, w0, b0);
        const float zr1 = fmaf(d1r*scale, w1, b1);
        const float zi0 = d0i*scale*w0;
        const float zi1 = d1i*scale*w1;

        const int col = h*DHEAD + lane;
        const size_t gbase = (size_t)row*(2*HIDDEN);
        const float gr0 = Graw[gbase + col];
        const float gr1 = Graw[gbase + col + 64];
        const float gi0 = Graw[gbase + HIDDEN + col];
        const float gi1 = Graw[gbase + HIDDEN + col + 64];

        float s0r, s0i, s1r, s1i;
        cswish(gr0, gi0, s0r, s0i);
        cswish(gr1, gi1, s1r, s1i);

        Aout[gbase + col]               = f2bf(s0r + zr0);
        Aout[gbase + col + 64]          = f2bf(s1r + zr1);
        Aout[gbase + HIDDEN + col]      = f2bf(s0i + zi0);
        Aout[gbase + HIDDEN + col + 64] = f2bf(s1i + zi1);
    }
}

// ---------------------------------------------------------------------------
extern "C" void kernel_launch(void* const* d_in, const int* in_sizes, int n_in,
                              void* d_out, int out_size, void* d_ws, size_t ws_size,
                              hipStream_t stream)
{
    (void)in_sizes; (void)n_in; (void)ws_size;

    const float* X     = (const float*)d_in[0];
    const float* Wq    = (const float*)d_in[1];
    const float* Wk    = (const float*)d_in[2];
    const float* Wv    = (const float*)d_in[3];
    const float* theta = (const float*)d_in[4];
    const float* gnw   = (const float*)d_in[5];
    const float* gnb   = (const float*)d_in[6];
    const float* Wgre  = (const float*)d_in[7];
    const float* Wgim  = (const float*)d_in[8];
    const float* Wore  = (const float*)d_in[9];
    const float* Woim  = (const float*)d_in[10];

    float* ws = (float*)d_ws;
    const size_t P = (size_t)NTOK*HIDDEN;          // 2M elements

    float* yre = ws;                               // [0, P)
    float* yim = ws + P;                           // [P, 2P)
    unsigned short* Qbre = (unsigned short*)(ws + 2*P);  // [2P,4P) as 4 x P ushort
    unsigned short* Qbim = Qbre + P;
    unsigned short* Kbre = Qbim + P;
    unsigned short* Kbim = Kbre + P;
    float* Graw = ws + 2*P;                        // alias Q/K (dead after attn), [2P,4P)
    float* vv   = ws + 4*P;                        // [4P,5P)
    unsigned short* Aout = (unsigned short*)(ws + 4*P);  // alias vv (dead after vt)
    unsigned short* Vtb  = (unsigned short*)(ws + 5*P);  // [5P,5.5P)
    unsigned short* Bot  = Vtb;                    // alias Vtb (dead after attn)
    unsigned short* Xb   = (unsigned short*)(ws + 5*P) + P;      // [5.5P,6P)
    unsigned short* Bgt  = (unsigned short*)(ws + 6*P);          // [6P,6.5P)
    unsigned short* Boti = (unsigned short*)(ws + 6*P) + P;      // [6.5P,7P) cplx only
    float* gpw = ws + 7*P;

    const int cplx = (out_size >= (int)(2*P)) ? 1 : 0;

    hipLaunchKernelGGL(gpow_kernel, dim3(NHEADS), dim3(SEQ), 0, stream, gpw);
    hipLaunchKernelGGL(proj_kernel, dim3(NTOK/64, NHEADS, 3), dim3(256), 0, stream,
                       X, Wq, Wk, Wv, theta, Qbre, Qbim, Kbre, Kbim, vv);
    hipLaunchKernelGGL(vt_kernel, dim3(NTOK/64, NHEADS), dim3(256), 0, stream, vv, Vtb);
    hipLaunchKernelGGL(attn_kernel, dim3(SEQ/32 * BATCH*NHEADS), dim3(128), 0, stream,
                       Qbre, Qbim, Kbre, Kbim, Vtb, gpw, yre, yim);

    // gating path (after attn: Graw aliases Q/K)
    hipLaunchKernelGGL(xprep_kernel, dim3(NTOK*HIDDEN/(256*8)), dim3(256), 0, stream, X, Xb);
    hipLaunchKernelGGL(wprep_g_kernel, dim3(2*HIDDEN/64, HIDDEN/64), dim3(256), 0, stream,
                       Wgre, Wgim, Bgt);
    hipLaunchKernelGGL(gemm_bf16_kernel, dim3(NTOK/128, 2*HIDDEN/128), dim3(256), 0, stream,
                       Xb, Bgt, Graw, HIDDEN, 2*HIDDEN, 0);

    // fused norm + swish + add -> bf16 A
    hipLaunchKernelGGL(znorm_kernel, dim3(NTOK), dim3(256), 0, stream,
                       yre, yim, Graw, gnw, gnb, Aout);

    // output projection
    hipLaunchKernelGGL(wprep_o_kernel, dim3(HIDDEN/64, 2*HIDDEN/64), dim3(256), 0, stream,
                       Wore, Woim, Bot, 0);
    if (!cplx) {
        hipLaunchKernelGGL(gemm_bf16_kernel, dim3(NTOK/128, HIDDEN/128), dim3(256), 0, stream,
                           Aout, Bot, (float*)d_out, 2*HIDDEN, HIDDEN, 0);
    } else {
        hipLaunchKernelGGL(wprep_o_kernel, dim3(HIDDEN/64, 2*HIDDEN/64), dim3(256), 0, stream,
                           Wore, Woim, Boti, 1);
        hipLaunchKernelGGL(gemm_bf16_kernel, dim3(NTOK/128, HIDDEN/128), dim3(256), 0, stream,
                           Aout, Bot, (float*)d_out, 2*HIDDEN, HIDDEN, 1);
        hipLaunchKernelGGL(gemm_bf16_kernel, dim3(NTOK/128, HIDDEN/128), dim3(256), 0, stream,
                           Aout, Boti, (float*)d_out, 2*HIDDEN, HIDDEN, 2);
    }
}

// Round 10
// 150.861 us; speedup vs baseline: 1.9376x; 1.9376x over previous
//
#include <hip/hip_runtime.h>
#include <math.h>

#define BATCH  2
#define SEQ    1024
#define HIDDEN 1024
#define NHEADS 8
#define DHEAD  128
#define NTOK   (BATCH*SEQ)
#define GEPS   1e-5f

typedef float f32x16 __attribute__((ext_vector_type(16)));
typedef __bf16 bf16x8 __attribute__((ext_vector_type(8)));
typedef unsigned int u32x4 __attribute__((ext_vector_type(4)));

union Frag { u32x4 u; bf16x8 h; };

__device__ __forceinline__ unsigned short f2bf(float f) {
    unsigned int u = __float_as_uint(f);
    unsigned int r = (u + 0x7FFFu + ((u >> 16) & 1u)) >> 16;
    return (unsigned short)r;
}

// complex swish: z * sigmoid(z)
__device__ __forceinline__ void cswish(float zr, float zi, float& outr, float& outi) {
    const float e = expf(-zr);
    float sg, cg;
    sincosf(zi, &sg, &cg);
    const float wr = fmaf(e, cg, 1.0f);   // 1 + e^{-zr} cos(zi)
    const float wi = -e*sg;               // -e^{-zr} sin(zi)
    const float inv = 1.0f / fmaf(wr, wr, wi*wi);
    outr = (zr*wr + zi*wi)*inv;
    outi = (zi*wr - zr*wi)*inv;
}

// ---------------------------------------------------------------------------
// gamma decay table
// ---------------------------------------------------------------------------
__global__ void gpow_kernel(float* __restrict__ gpow) {
    const int h = blockIdx.x;
    const int k = threadIdx.x;
    const float l = fmaf((float)h, -0.39608410317711170f, -3.46573590279972650f);
    const float gamma = 1.0f - expf(l);
    gpow[h*SEQ + k] = powf(gamma, (float)k);
}

// ---------------------------------------------------------------------------
// X fp32 -> bf16 pack (runs first; Xb feeds proj AND gemm g)
// ---------------------------------------------------------------------------
__global__ __launch_bounds__(256) void xprep_kernel(
    const float* __restrict__ X, unsigned short* __restrict__ Xb)
{
    const size_t i = ((size_t)blockIdx.x*256 + threadIdx.x)*8;
    const float4 a = *(const float4*)&X[i];
    const float4 b = *(const float4*)&X[i+4];
    __align__(16) unsigned short t[8] = { f2bf(a.x), f2bf(a.y), f2bf(a.z), f2bf(a.w),
                                          f2bf(b.x), f2bf(b.y), f2bf(b.z), f2bf(b.w) };
    *(u32x4*)&Xb[i] = *(u32x4*)t;
}

// ---------------------------------------------------------------------------
// Wqkv^T pack: Wt[type][h][n][k] bf16 <- W[type][h][k][n] fp32
// grid (24, 4): x = type*8+h, y = (kq<<1)|nq  (64x64 subtile)
// ---------------------------------------------------------------------------
__global__ __launch_bounds__(256) void wprep_qkv_kernel(
    const float* __restrict__ Wq, const float* __restrict__ Wk, const float* __restrict__ Wv,
    unsigned short* __restrict__ Wt)
{
    const int th_ = blockIdx.x;           // type*8 + h
    const int type = th_ >> 3, h = th_ & 7;
    const int k0 = (blockIdx.y >> 1)*64, n0 = (blockIdx.y & 1)*64;
    const float* W = ((type == 0) ? Wq : (type == 1) ? Wk : Wv)
                     + (size_t)h*DHEAD*DHEAD;
    __shared__ float Ws[64][65];
    const int tid = threadIdx.x;
    #pragma unroll
    for (int it = 0; it < 4; ++it) {
        const int r = (tid >> 4) + it*16, c = (tid & 15)*4;
        *(float4*)&Ws[r][c] = *(const float4*)&W[(size_t)(k0 + r)*DHEAD + n0 + c];
    }
    __syncthreads();
    const int nl = tid >> 2, seg = (tid & 3)*16;
    __align__(16) unsigned short t[16];
    #pragma unroll
    for (int j = 0; j < 16; ++j) t[j] = f2bf(Ws[seg + j][nl]);
    u32x4* d = (u32x4*)&Wt[((size_t)th_*DHEAD + n0 + nl)*DHEAD + k0 + seg];
    d[0] = ((u32x4*)t)[0];
    d[1] = ((u32x4*)t)[1];
}

// ---------------------------------------------------------------------------
// MFMA projections + fused RoPE: Q/K bf16, V fp32.
// block = (64-token tile, head, type); 4 waves = 2 token-halves x 2 n-halves;
// each wave: 2 n-tiles of 32x32, K=128 (8 mfma each). A from Xb, B from Wt.
// ---------------------------------------------------------------------------
__global__ __launch_bounds__(256) void projm_kernel(
    const unsigned short* __restrict__ Xb,
    const unsigned short* __restrict__ Wt,
    const float* __restrict__ theta,
    unsigned short* __restrict__ Qbre, unsigned short* __restrict__ Qbim,
    unsigned short* __restrict__ Kbre, unsigned short* __restrict__ Kbim,
    float* __restrict__ vv)
{
    const int tt = blockIdx.x;
    const int h  = blockIdx.y;
    const int mt = blockIdx.z;       // 0:q 1:k 2:v
    const int tid = threadIdx.x;
    const int w = tid >> 6, lane = tid & 63;
    const int th = w >> 1, nh = w & 1;
    const int l31 = lane & 31, hi = (lane >> 5) & 1;

    // A fragments: token rows th*32+l31, k-chunks
    Frag A[8];
    {
        const unsigned short* xa = Xb + (size_t)(tt*64 + th*32 + l31)*HIDDEN
                                   + h*DHEAD + 8*hi;
        #pragma unroll
        for (int ks = 0; ks < 8; ++ks) A[ks].u = *(const u32x4*)(xa + 16*ks);
    }

    const unsigned short* wb = Wt + (size_t)(mt*NHEADS + h)*DHEAD*DHEAD;

    #pragma unroll
    for (int nt = 0; nt < 2; ++nt) {
        const int n0 = nh*64 + nt*32;
        const int n  = n0 + l31;

        Frag B[8];
        const unsigned short* wp = wb + (size_t)n*DHEAD + 8*hi;
        #pragma unroll
        for (int ks = 0; ks < 8; ++ks) B[ks].u = *(const u32x4*)(wp + 16*ks);

        f32x16 acc;
        #pragma unroll
        for (int e = 0; e < 16; ++e) acc[e] = 0.f;
        #pragma unroll
        for (int ks = 0; ks < 8; ++ks)
            acc = __builtin_amdgcn_mfma_f32_32x32x16_bf16(A[ks].h, B[ks].h, acc, 0, 0, 0);

        if (mt == 2) {
            #pragma unroll
            for (int r = 0; r < 16; ++r) {
                const int row = (r & 3) + 8*(r >> 2) + 4*hi;
                const int tok = tt*64 + th*32 + row;
                vv[(size_t)tok*HIDDEN + h*DHEAD + n] = acc[r];
            }
        } else {
            const float thv = theta[h*DHEAD + n];
            unsigned short* pre = (mt == 0) ? Qbre : Kbre;
            unsigned short* pim = (mt == 0) ? Qbim : Kbim;
            const float sgn = (mt == 0) ? 1.0f : -1.0f;
            #pragma unroll
            for (int r = 0; r < 16; ++r) {
                const int row = (r & 3) + 8*(r >> 2) + 4*hi;
                const int tok = tt*64 + th*32 + row;
                const float np1 = (float)((tok & (SEQ-1)) + 1);
                float s, c;
                sincosf(np1*thv, &s, &c);
                const size_t g = (size_t)tok*HIDDEN + h*DHEAD + n;
                pre[g] = f2bf(acc[r]*c);
                pim[g] = f2bf(acc[r]*s*sgn);
            }
        }
    }
}

// ---------------------------------------------------------------------------
// V transpose: vv fp32 [token][h*128+d] -> Vtb bf16 [bh][d][s]
// ---------------------------------------------------------------------------
__global__ __launch_bounds__(256) void vt_kernel(
    const float* __restrict__ vv, unsigned short* __restrict__ Vtb)
{
    const int st  = blockIdx.x;
    const int h   = blockIdx.y;
    const int tid = threadIdx.x;
    const int b  = st >> 4;
    const int s0 = (st & 15)*64;

    __shared__ __align__(16) float Vs[64][132];

    for (int i = tid*4; i < 64*128; i += 1024) {
        const int r = i >> 7, c = i & 127;
        *(float4*)&Vs[r][c] = *(const float4*)&vv[(size_t)(st*64 + r)*HIDDEN + h*DHEAD + c];
    }
    __syncthreads();

    const int d = tid & 127, seg = tid >> 7;
    unsigned short* dst = Vtb + ((size_t)((b*NHEADS + h)*DHEAD + d))*SEQ + s0 + seg*32;
    #pragma unroll
    for (int j = 0; j < 32; j += 2) {
        unsigned int u = (unsigned)f2bf(Vs[seg*32+j][d]) | ((unsigned)f2bf(Vs[seg*32+j+1][d]) << 16);
        *(unsigned int*)(dst + j) = u;
    }
}

// ---------------------------------------------------------------------------
// retention attention, MFMA bf16 — ROUND-5 STRUCTURE (proven 61 us):
// 2 waves/block split the causal m-range; all state in registers; LDS combine;
// XCD-chunked grid.
// ---------------------------------------------------------------------------
#define CVTPK(dst, a, b) asm("v_cvt_pk_bf16_f32 %0, %1, %2" : "=v"(dst) : "v"(a), "v"(b))
#define SWAP32(x, y)     asm("v_permlane32_swap_b32 %0, %1" : "+v"(x), "+v"(y))

__global__ __launch_bounds__(128) void attn_kernel(
    const unsigned short* __restrict__ Qbre, const unsigned short* __restrict__ Qbim,
    const unsigned short* __restrict__ Kbre, const unsigned short* __restrict__ Kbim,
    const unsigned short* __restrict__ Vtb,  const float* __restrict__ gpow,
    float* __restrict__ yre, float* __restrict__ yim)
{
    const int tid  = threadIdx.x;
    const int lane = tid & 63;
    const int wv   = tid >> 6;
    const int l31 = lane & 31, hi = (lane >> 5) & 1;

    // XCD-chunked decode: id%8 = bh>>1  (each XCD owns 2 (b,h) pairs)
    const int id = blockIdx.x;
    const int bh = ((id & 7) << 1) | ((id >> 3) & 1);
    const int qt = id >> 4;

    const int b = bh >> 3, h = bh & 7;
    const int q0 = qt * 32;
    const size_t bhoff = (size_t)b*SEQ*HIDDEN + h*DHEAD;
    const float* gp = gpow + h*SEQ;

    __shared__ float Yt2[32][133];

    int   crw[16];
    float ginv[16];
    #pragma unroll
    for (int r = 0; r < 16; ++r) {
        const int cr = (r & 3) + 8*(r >> 2) + 4*hi;
        crw[r] = cr;
        ginv[r] = 1.0f / gp[cr];
    }

    Frag Qr[8], Qi[8];
    {
        const unsigned short* qr = Qbre + bhoff + (size_t)(q0 + l31)*HIDDEN + 8*hi;
        const unsigned short* qi = Qbim + bhoff + (size_t)(q0 + l31)*HIDDEN + 8*hi;
        #pragma unroll
        for (int ks = 0; ks < 8; ++ks) {
            Qr[ks].u = *(const u32x4*)(qr + 16*ks);
            Qi[ks].u = *(const u32x4*)(qi + 16*ks);
        }
    }

    f32x16 Yr[4], Yi[4];
    #pragma unroll
    for (int dt = 0; dt < 4; ++dt)
        #pragma unroll
        for (int e = 0; e < 16; ++e) { Yr[dt][e] = 0.f; Yi[dt][e] = 0.f; }

    // m-range split across the 2 waves
    const int nm   = qt + 1;
    const int half = (nm + 1) >> 1;
    const int mlo  = wv ? half : 0;
    const int mhi  = wv ? nm   : half;

    #pragma unroll 1
    for (int m = mlo; m < mhi; ++m) {
        const int kv0 = m*32;

        Frag Kr[8], Ki[8];
        {
            const unsigned short* kr = Kbre + bhoff + (size_t)(kv0 + l31)*HIDDEN + 8*hi;
            const unsigned short* ki = Kbim + bhoff + (size_t)(kv0 + l31)*HIDDEN + 8*hi;
            #pragma unroll
            for (int ks = 0; ks < 8; ++ks) {
                Kr[ks].u = *(const u32x4*)(kr + 16*ks);
                Ki[ks].u = *(const u32x4*)(ki + 16*ks);
            }
        }
        Frag Vf[4][2];
        #pragma unroll
        for (int dt = 0; dt < 4; ++dt)
            #pragma unroll
            for (int ks2 = 0; ks2 < 2; ++ks2)
                Vf[dt][ks2].u = *(const u32x4*)(Vtb + ((size_t)(bh*DHEAD + dt*32 + l31))*SEQ
                                                + kv0 + 16*ks2 + 8*hi);

        const int  base = 32*(qt - m) + l31;
        const float g1  = gp[base];

        f32x16 SR, SI;
        #pragma unroll
        for (int e = 0; e < 16; ++e) { SR[e] = 0.f; SI[e] = 0.f; }
        #pragma unroll
        for (int ks = 0; ks < 8; ++ks) {
            Frag Qin;
            #pragma unroll
            for (int e = 0; e < 4; ++e) Qin.u[e] = Qi[ks].u[e] ^ 0x80008000u;
            SR = __builtin_amdgcn_mfma_f32_32x32x16_bf16(Kr[ks].h, Qr[ks].h, SR, 0, 0, 0);
            SI = __builtin_amdgcn_mfma_f32_32x32x16_bf16(Kr[ks].h, Qi[ks].h, SI, 0, 0, 0);
            SR = __builtin_amdgcn_mfma_f32_32x32x16_bf16(Ki[ks].h, Qin.h, SR, 0, 0, 0);
            SI = __builtin_amdgcn_mfma_f32_32x32x16_bf16(Ki[ks].h, Qr[ks].h, SI, 0, 0, 0);
        }

        float pr[16], pi[16];
        #pragma unroll
        for (int r = 0; r < 16; ++r) {
            const float w = (base >= crw[r]) ? g1*ginv[r] : 0.0f;
            pr[r] = SR[r]*w;
            pi[r] = SI[r]*w;
        }

        Frag PR[2], PI[2];
        #pragma unroll
        for (int ks2 = 0; ks2 < 2; ++ks2) {
            const int o = ks2*8;
            unsigned int a0, b0, a1, b1;
            CVTPK(a0, pr[o+0], pr[o+1]);
            CVTPK(b0, pr[o+4], pr[o+5]);
            SWAP32(a0, b0);
            CVTPK(a1, pr[o+2], pr[o+3]);
            CVTPK(b1, pr[o+6], pr[o+7]);
            SWAP32(a1, b1);
            PR[ks2].u[0] = a0; PR[ks2].u[1] = a1; PR[ks2].u[2] = b0; PR[ks2].u[3] = b1;
            CVTPK(a0, pi[o+0], pi[o+1]);
            CVTPK(b0, pi[o+4], pi[o+5]);
            SWAP32(a0, b0);
            CVTPK(a1, pi[o+2], pi[o+3]);
            CVTPK(b1, pi[o+6], pi[o+7]);
            SWAP32(a1, b1);
            PI[ks2].u[0] = a0; PI[ks2].u[1] = a1; PI[ks2].u[2] = b0; PI[ks2].u[3] = b1;
        }

        #pragma unroll
        for (int dt = 0; dt < 4; ++dt) {
            Yr[dt] = __builtin_amdgcn_mfma_f32_32x32x16_bf16(Vf[dt][0].h, PR[0].h, Yr[dt], 0, 0, 0);
            Yr[dt] = __builtin_amdgcn_mfma_f32_32x32x16_bf16(Vf[dt][1].h, PR[1].h, Yr[dt], 0, 0, 0);
            Yi[dt] = __builtin_amdgcn_mfma_f32_32x32x16_bf16(Vf[dt][0].h, PI[0].h, Yi[dt], 0, 0, 0);
            Yi[dt] = __builtin_amdgcn_mfma_f32_32x32x16_bf16(Vf[dt][1].h, PI[1].h, Yi[dt], 0, 0, 0);
        }
    }

    // combine the 2 waves' partials + transposed coalesced store
    #pragma unroll
    for (int part = 0; part < 2; ++part) {
        if (part) __syncthreads();
        if (wv == 0) {
            #pragma unroll
            for (int dt = 0; dt < 4; ++dt)
                #pragma unroll
                for (int r = 0; r < 16; ++r)
                    Yt2[l31][dt*32 + crw[r]] = part ? Yi[dt][r] : Yr[dt][r];
        }
        __syncthreads();
        if (wv == 1) {
            #pragma unroll
            for (int dt = 0; dt < 4; ++dt)
                #pragma unroll
                for (int r = 0; r < 16; ++r)
                    Yt2[l31][dt*32 + crw[r]] += part ? Yi[dt][r] : Yr[dt][r];
        }
        __syncthreads();
        const int t = tid >> 2, q4 = tid & 3;
        float* dst = (part ? yim : yre) + bhoff + (size_t)(q0 + t)*HIDDEN + q4*32;
        #pragma unroll
        for (int j = 0; j < 8; ++j) {
            float4 o;
            o.x = Yt2[t][q4*32 + 4*j + 0];
            o.y = Yt2[t][q4*32 + 4*j + 1];
            o.z = Yt2[t][q4*32 + 4*j + 2];
            o.w = Yt2[t][q4*32 + 4*j + 3];
            *(float4*)(dst + 4*j) = o;
        }
    }
}

// ---------------------------------------------------------------------------
// Bgt[n][k] = (n<1024 ? Wgre : Wgim)[k][n&1023]  -- bf16, [2048][1024]
// ---------------------------------------------------------------------------
__global__ __launch_bounds__(256) void wprep_g_kernel(
    const float* __restrict__ Wgre, const float* __restrict__ Wgim,
    unsigned short* __restrict__ Bgt)
{
    const int n0 = blockIdx.x*64, k0 = blockIdx.y*64;
    const float* src = (n0 < HIDDEN) ? Wgre : Wgim;
    const int nc = n0 & (HIDDEN-1);
    __shared__ float Ws[64][65];
    const int tid = threadIdx.x;
    #pragma unroll
    for (int it = 0; it < 4; ++it) {
        const int r = (tid >> 4) + it*16, c = (tid & 15)*4;
        *(float4*)&Ws[r][c] = *(const float4*)&src[(size_t)(k0 + r)*HIDDEN + nc + c];
    }
    __syncthreads();
    const int nl = tid >> 2, seg = (tid & 3)*16;
    __align__(16) unsigned short t[16];
    #pragma unroll
    for (int j = 0; j < 16; ++j) t[j] = f2bf(Ws[seg + j][nl]);
    u32x4* d = (u32x4*)&Bgt[(size_t)(n0 + nl)*HIDDEN + k0 + seg];
    d[0] = ((u32x4*)t)[0];
    d[1] = ((u32x4*)t)[1];
}

// ---------------------------------------------------------------------------
// Bot[n][k] (bf16, [1024][2048]):
//   imMode=0: k<1024 ?  Wore[k][n] : -Woim[k-1024][n]   (real-part weights)
//   imMode=1: k<1024 ?  Woim[k][n] :  Wore[k-1024][n]   (imag-part weights)
// ---------------------------------------------------------------------------
__global__ __launch_bounds__(256) void wprep_o_kernel(
    const float* __restrict__ Wore, const float* __restrict__ Woim,
    unsigned short* __restrict__ Bot, const int imMode)
{
    const int n0 = blockIdx.x*64, k0 = blockIdx.y*64;
    const float* src;
    float sign = 1.0f;
    if (!imMode) { if (k0 < HIDDEN) src = Wore; else { src = Woim; sign = -1.0f; } }
    else         { src = (k0 < HIDDEN) ? Woim : Wore; }
    const int kc = k0 & (HIDDEN-1);
    __shared__ float Ws[64][65];
    const int tid = threadIdx.x;
    #pragma unroll
    for (int it = 0; it < 4; ++it) {
        const int r = (tid >> 4) + it*16, c = (tid & 15)*4;
        const float4 v = *(const float4*)&src[(size_t)(kc + r)*HIDDEN + n0 + c];
        Ws[r][c+0] = v.x*sign; Ws[r][c+1] = v.y*sign; Ws[r][c+2] = v.z*sign; Ws[r][c+3] = v.w*sign;
    }
    __syncthreads();
    const int nl = tid >> 2, seg = (tid & 3)*16;
    __align__(16) unsigned short t[16];
    #pragma unroll
    for (int j = 0; j < 16; ++j) t[j] = f2bf(Ws[seg + j][nl]);
    u32x4* d = (u32x4*)&Bot[(size_t)(n0 + nl)*(2*HIDDEN) + k0 + seg];
    d[0] = ((u32x4*)t)[0];
    d[1] = ((u32x4*)t)[1];
}

// ---------------------------------------------------------------------------
// generic bf16 MFMA GEMM: C[M][N] = A[M][K] @ Bt[N][K]^T
// 128x128 tile, BK=64, 4 waves (2x2 of 32x32x16 frags each).
// mode 0: plain fp32 store; mode 1/2: interleaved complex re/im store.
// ---------------------------------------------------------------------------
__global__ __launch_bounds__(256) void gemm_bf16_kernel(
    const unsigned short* __restrict__ A,
    const unsigned short* __restrict__ Bt,
    float* __restrict__ C,
    const int K, const int N, const int mode)
{
    __shared__ __align__(16) unsigned short As[128][72];
    __shared__ __align__(16) unsigned short Bs[128][72];

    const int tid = threadIdx.x;
    const int mb = blockIdx.x, nb = blockIdx.y;
    const int lane = tid & 63, w = tid >> 6;
    const int l31 = lane & 31, hi = lane >> 5;
    const int wm = (w >> 1) * 64, wn = (w & 1) * 64;

    const int srow = tid >> 2;          // 0..63
    const int sseg = (tid & 3) * 16;    // 0,16,32,48 (full 64-col tile)

    const unsigned short* ga = A  + (size_t)(mb*128 + srow)*K + sseg;
    const unsigned short* gb = Bt + (size_t)(nb*128 + srow)*K + sseg;

    f32x16 acc00, acc01, acc10, acc11;
    #pragma unroll
    for (int e = 0; e < 16; ++e) { acc00[e]=0.f; acc01[e]=0.f; acc10[e]=0.f; acc11[e]=0.f; }

    u32x4 ra0 = *(const u32x4*)(ga);
    u32x4 ra1 = *(const u32x4*)(ga + 8);
    u32x4 ra2 = *(const u32x4*)(ga + (size_t)64*K);
    u32x4 ra3 = *(const u32x4*)(ga + (size_t)64*K + 8);
    u32x4 rb0 = *(const u32x4*)(gb);
    u32x4 rb1 = *(const u32x4*)(gb + 8);
    u32x4 rb2 = *(const u32x4*)(gb + (size_t)64*K);
    u32x4 rb3 = *(const u32x4*)(gb + (size_t)64*K + 8);

    for (int kk = 0; kk < K; kk += 64) {
        __syncthreads();
        *(u32x4*)&As[srow][sseg]          = ra0;
        *(u32x4*)&As[srow][sseg + 8]      = ra1;
        *(u32x4*)&As[srow + 64][sseg]     = ra2;
        *(u32x4*)&As[srow + 64][sseg + 8] = ra3;
        *(u32x4*)&Bs[srow][sseg]          = rb0;
        *(u32x4*)&Bs[srow][sseg + 8]      = rb1;
        *(u32x4*)&Bs[srow + 64][sseg]     = rb2;
        *(u32x4*)&Bs[srow + 64][sseg + 8] = rb3;
        if (kk + 64 < K) {
            const int o = kk + 64;
            ra0 = *(const u32x4*)(ga + o);
            ra1 = *(const u32x4*)(ga + o + 8);
            ra2 = *(const u32x4*)(ga + (size_t)64*K + o);
            ra3 = *(const u32x4*)(ga + (size_t)64*K + o + 8);
            rb0 = *(const u32x4*)(gb + o);
            rb1 = *(const u32x4*)(gb + o + 8);
            rb2 = *(const u32x4*)(gb + (size_t)64*K + o);
            rb3 = *(const u32x4*)(gb + (size_t)64*K + o + 8);
        }
        __syncthreads();
        #pragma unroll
        for (int ks = 0; ks < 4; ++ks) {
            Frag a0, a1, b0, b1;
            a0.u = *(const u32x4*)&As[wm + l31     ][ks*16 + hi*8];
            a1.u = *(const u32x4*)&As[wm + l31 + 32][ks*16 + hi*8];
            b0.u = *(const u32x4*)&Bs[wn + l31     ][ks*16 + hi*8];
            b1.u = *(const u32x4*)&Bs[wn + l31 + 32][ks*16 + hi*8];
            acc00 = __builtin_amdgcn_mfma_f32_32x32x16_bf16(a0.h, b0.h, acc00, 0, 0, 0);
            acc01 = __builtin_amdgcn_mfma_f32_32x32x16_bf16(a0.h, b1.h, acc01, 0, 0, 0);
            acc10 = __builtin_amdgcn_mfma_f32_32x32x16_bf16(a1.h, b0.h, acc10, 0, 0, 0);
            acc11 = __builtin_amdgcn_mfma_f32_32x32x16_bf16(a1.h, b1.h, acc11, 0, 0, 0);
        }
    }

    const int cb = nb*128 + wn + l31;
    #pragma unroll
    for (int i = 0; i < 2; ++i) {
        const f32x16& c0 = i ? acc10 : acc00;
        const f32x16& c1 = i ? acc11 : acc01;
        #pragma unroll
        for (int r = 0; r < 16; ++r) {
            const int row = mb*128 + wm + 32*i + (r & 3) + 8*(r >> 2) + 4*hi;
            if (mode == 0) {
                float* cr = C + (size_t)row*N + cb;
                cr[0]  = c0[r];
                cr[32] = c1[r];
            } else {
                float* cr = C + ((size_t)row*N + cb)*2 + (mode - 1);
                cr[0]  = c0[r];
                cr[64] = c1[r];
            }
        }
    }
}

// ---------------------------------------------------------------------------
// fused: group-norm(Y) + swish(G) + add -> Aout bf16 [2048][2048] (Zr | Zi)
// ---------------------------------------------------------------------------
__global__ __launch_bounds__(256) void znorm_kernel(
    const float* __restrict__ yre, const float* __restrict__ yim,
    const float* __restrict__ Graw,
    const float* __restrict__ w, const float* __restrict__ bbv,
    unsigned short* __restrict__ Aout)
{
    const int row  = blockIdx.x;
    const int wv   = threadIdx.x >> 6;
    const int lane = threadIdx.x & 63;

    #pragma unroll
    for (int gi = 0; gi < 2; ++gi) {
        const int h = wv*2 + gi;
        const size_t base = (size_t)row*HIDDEN + h*DHEAD;

        const float r0 = yre[base + lane];
        const float r1 = yre[base + lane + 64];
        const float i0 = yim[base + lane];
        const float i1 = yim[base + lane + 64];

        float sr = r0 + r1, si = i0 + i1;
        #pragma unroll
        for (int off = 32; off > 0; off >>= 1) {
            sr += __shfl_xor(sr, off);
            si += __shfl_xor(si, off);
        }
        const float mr = sr * (1.0f/128.0f), mi = si * (1.0f/128.0f);
        const float d0r = r0 - mr, d1r = r1 - mr, d0i = i0 - mi, d1i = i1 - mi;
        float vs = d0r*d0r + d0i*d0i + d1r*d1r + d1i*d1i;
        #pragma unroll
        for (int off = 32; off > 0; off >>= 1) vs += __shfl_xor(vs, off);
        const float scale = 1.0f / sqrtf(vs * (1.0f/127.0f) + GEPS);

        const float w0 = w[h*DHEAD + lane],   w1 = w[h*DHEAD + lane + 64];
        const float b0 = bbv[h*DHEAD + lane], b1 = bbv[h*DHEAD + lane + 64];
        const float zr0 = fmaf(d0r*scale, w0, b0);
        const float zr1 = fmaf(d1r*scale, w1, b1);
        const float zi0 = d0i*scale*w0;
        const float zi1 = d1i*scale*w1;

        const int col = h*DHEAD + lane;
        const size_t gbase = (size_t)row*(2*HIDDEN);
        const float gr0 = Graw[gbase + col];
        const float gr1 = Graw[gbase + col + 64];
        const float gi0 = Graw[gbase + HIDDEN + col];
        const float gi1 = Graw[gbase + HIDDEN + col + 64];

        float s0r, s0i, s1r, s1i;
        cswish(gr0, gi0, s0r, s0i);
        cswish(gr1, gi1, s1r, s1i);

        Aout[gbase + col]               = f2bf(s0r + zr0);
        Aout[gbase + col + 64]          = f2bf(s1r + zr1);
        Aout[gbase + HIDDEN + col]      = f2bf(s0i + zi0);
        Aout[gbase + HIDDEN + col + 64] = f2bf(s1i + zi1);
    }
}

// ---------------------------------------------------------------------------
extern "C" void kernel_launch(void* const* d_in, const int* in_sizes, int n_in,
                              void* d_out, int out_size, void* d_ws, size_t ws_size,
                              hipStream_t stream)
{
    (void)in_sizes; (void)n_in; (void)ws_size;

    const float* X     = (const float*)d_in[0];
    const float* Wq    = (const float*)d_in[1];
    const float* Wk    = (const float*)d_in[2];
    const float* Wv    = (const float*)d_in[3];
    const float* theta = (const float*)d_in[4];
    const float* gnw   = (const float*)d_in[5];
    const float* gnb   = (const float*)d_in[6];
    const float* Wgre  = (const float*)d_in[7];
    const float* Wgim  = (const float*)d_in[8];
    const float* Wore  = (const float*)d_in[9];
    const float* Woim  = (const float*)d_in[10];

    float* ws = (float*)d_ws;
    const size_t P = (size_t)NTOK*HIDDEN;          // 2M elements

    float* yre = ws;                               // [0, P)
    float* yim = ws + P;                           // [P, 2P)
    unsigned short* Qbre = (unsigned short*)(ws + 2*P);  // [2P,4P) as 4 x P ushort
    unsigned short* Qbim = Qbre + P;
    unsigned short* Kbre = Qbim + P;
    unsigned short* Kbim = Kbre + P;
    float* Graw = ws + 2*P;                        // alias Q/K (dead after attn), [2P,4P)
    float* vv   = ws + 4*P;                        // [4P,5P)
    unsigned short* Aout = (unsigned short*)(ws + 4*P);  // alias vv (dead after vt)
    unsigned short* Vtb  = (unsigned short*)(ws + 5*P);  // [5P,5.5P)
    unsigned short* Bot  = Vtb;                    // alias Vtb (dead after attn)
    unsigned short* Xb   = (unsigned short*)(ws + 5*P) + P;      // [5.5P,6P)
    unsigned short* Bgt  = (unsigned short*)(ws + 6*P);          // [6P,6.5P)
    unsigned short* Wt   = (unsigned short*)(ws + 6*P) + P;      // [6.5P,7P): Wqkv^T (early)
    unsigned short* Boti = Wt;                     // cplx only; overwrites Wt after proj
    float* gpw = ws + 7*P;

    const int cplx = (out_size >= (int)(2*P)) ? 1 : 0;

    hipLaunchKernelGGL(gpow_kernel, dim3(NHEADS), dim3(SEQ), 0, stream, gpw);
    hipLaunchKernelGGL(xprep_kernel, dim3(NTOK*HIDDEN/(256*8)), dim3(256), 0, stream, X, Xb);
    hipLaunchKernelGGL(wprep_qkv_kernel, dim3(3*NHEADS, 4), dim3(256), 0, stream,
                       Wq, Wk, Wv, Wt);
    hipLaunchKernelGGL(projm_kernel, dim3(NTOK/64, NHEADS, 3), dim3(256), 0, stream,
                       Xb, Wt, theta, Qbre, Qbim, Kbre, Kbim, vv);
    hipLaunchKernelGGL(vt_kernel, dim3(NTOK/64, NHEADS), dim3(256), 0, stream, vv, Vtb);
    hipLaunchKernelGGL(attn_kernel, dim3(SEQ/32 * BATCH*NHEADS), dim3(128), 0, stream,
                       Qbre, Qbim, Kbre, Kbim, Vtb, gpw, yre, yim);

    // gating path (after attn: Graw aliases Q/K)
    hipLaunchKernelGGL(wprep_g_kernel, dim3(2*HIDDEN/64, HIDDEN/64), dim3(256), 0, stream,
                       Wgre, Wgim, Bgt);
    hipLaunchKernelGGL(gemm_bf16_kernel, dim3(NTOK/128, 2*HIDDEN/128), dim3(256), 0, stream,
                       Xb, Bgt, Graw, HIDDEN, 2*HIDDEN, 0);

    // fused norm + swish + add -> bf16 A
    hipLaunchKernelGGL(znorm_kernel, dim3(NTOK), dim3(256), 0, stream,
                       yre, yim, Graw, gnw, gnb, Aout);

    // output projection
    hipLaunchKernelGGL(wprep_o_kernel, dim3(HIDDEN/64, 2*HIDDEN/64), dim3(256), 0, stream,
                       Wore, Woim, Bot, 0);
    if (!cplx) {
        hipLaunchKernelGGL(gemm_bf16_kernel, dim3(NTOK/128, HIDDEN/128), dim3(256), 0, stream,
                           Aout, Bot, (float*)d_out, 2*HIDDEN, HIDDEN, 0);
    } else {
        hipLaunchKernelGGL(wprep_o_kernel, dim3(HIDDEN/64, 2*HIDDEN/64), dim3(256), 0, stream,
                           Wore, Woim, Boti, 1);
        hipLaunchKernelGGL(gemm_bf16_kernel, dim3(NTOK/128, HIDDEN/128), dim3(256), 0, stream,
                           Aout, Bot, (float*)d_out, 2*HIDDEN, HIDDEN, 1);
        hipLaunchKernelGGL(gemm_bf16_kernel, dim3(NTOK/128, HIDDEN/128), dim3(256), 0, stream,
                           Aout, Boti, (float*)d_out, 2*HIDDEN, HIDDEN, 2);
    }
}